// Round 8
// baseline (145.914 us; speedup 1.0000x reference)
//
#include <hip/hip_runtime.h>
#include <stdint.h>

#define B_DIM 16384
#define L_DIM 4096
#define H_DIM 256
#define LN_EPS 1e-5f

typedef unsigned short u16;
typedef __attribute__((ext_vector_type(4))) float f32x4;
typedef __attribute__((ext_vector_type(8))) short short8;

__device__ __forceinline__ u16 f2bf(float f) {
  union { float f; uint32_t u; } v; v.f = f;
  uint32_t u = v.u;
  u += 0x7FFFu + ((u >> 16) & 1u);   // round-to-nearest-even
  return (u16)(u >> 16);
}

__device__ __forceinline__ void store_bf4(void* p, float4 v) {
  ushort4 o; o.x = f2bf(v.x); o.y = f2bf(v.y); o.z = f2bf(v.z); o.w = f2bf(v.w);
  *(ushort4*)p = o;
}

__device__ __forceinline__ void gload_lds16(const void* g, void* l) {
  __builtin_amdgcn_global_load_lds((const __attribute__((address_space(1))) void*)g,
                                   (__attribute__((address_space(3))) void*)l, 16, 0, 0);
}

// Fragment-major prep: frag = kstep*16 + nt;
// dst[frag][lane][j] = bf16(src[row][nt*16 + (lane&15)]),
// row = idx ? idx[kstep*32+(lane>>4)*8+j] : (kstep*32+(lane>>4)*8+j)
__global__ __launch_bounds__(256) void prep_frag(const float* __restrict__ src,
                                                 const int* __restrict__ idx,
                                                 u16* __restrict__ dst) {
  const int t = threadIdx.x;
  const int l = t & 63;
  const int w = t >> 6;
  const int frag = blockIdx.x * 4 + w;
  const int kstep = frag >> 4;
  const int nt = frag & 15;
  const int n = nt * 16 + (l & 15);
  const int kbase = kstep * 32 + (l >> 4) * 8;
  short8 v;
#pragma unroll
  for (int j = 0; j < 8; ++j) {
    const int k = kbase + j;
    const int g = idx ? idx[k] : k;
    v[j] = (short)f2bf(src[(size_t)g * H_DIM + n]);
  }
  *reinterpret_cast<short8*>(dst + ((size_t)frag * 64 + l) * 8) = v;
}

// dst[n][k ^ ((n&7)<<3)] = bf16(src[k][n])  — transpose+cast+pre-swizzle (W1, R3-proven)
__global__ __launch_bounds__(256) void prep_tr(const float* __restrict__ src,
                                               const int* __restrict__ idx,
                                               u16* __restrict__ dst,
                                               int Ktot, int srcW) {
  __shared__ u16 tile[64][66];
  const int t = threadIdx.x;
  const int k0 = blockIdx.x * 64;
  const int n0 = blockIdx.y * 64;
  for (int r0 = 0; r0 < 64; r0 += 4) {
    const int kk = k0 + r0 + (t >> 6);
    const int nn = n0 + (t & 63);
    const int srow = idx ? idx[kk] : kk;
    tile[r0 + (t >> 6)][t & 63] = f2bf(src[(size_t)srow * srcW + nn]);
  }
  __syncthreads();
  for (int c = t; c < 512; c += 256) {
    const int n = c >> 3;
    const int inner = c & 7;
    const int nG = n0 + n;
    short8 v;
#pragma unroll
    for (int j = 0; j < 8; ++j) v[j] = (short)tile[inner * 8 + j][n];
    const size_t didx = (size_t)nG * Ktot + (size_t)k0 +
                        (size_t)((inner * 8) ^ ((nG & 7) << 3));
    *reinterpret_cast<short8*>(dst + didx) = v;
  }
}

// GEMM1: h[16384,256] = x @ feat. BM=64, 512 thr = 2 k-groups x (2m x 2n).
// Each group streams its K=2048 half in 64 BK=32 stages with private buffers:
//   B: 16KB/stage via gload_lds (fragment-major, L2-resident), dbuf.
//   A: global->reg f32 -> bf16 -> swizzled ds_write_b64, dbuf (bf16 halves LDS bytes).
// LDS-port model: 120KB/stage/CU (was 240KB) -> ~30us port floor.
// vmcnt(0) only (order-independent). End: kh1 stages acc f32 in LDS, kh0 adds
// and writes h_s bf16 pre-swizzled (R3 layout for gemm2's gload_lds).
__global__ __launch_bounds__(512, 2) void gemm1(const float* __restrict__ x,
                                                const u16* __restrict__ fragB,
                                                u16* __restrict__ h_s) {
  __shared__ __align__(16) char pool[81920];  // B:[kh][2][16K] @0; A:[kh][2][4K] @65536
  const int t = threadIdx.x;
  const int l = t & 63;
  const int w = t >> 6;        // 0..7
  const int kh = w >> 2;       // k-half group
  const int wq = w & 3;
  const int wm = wq >> 1;      // 32-row slice
  const int wn = wq & 1;       // 128-col half
  const int m0 = blockIdx.x * 64;
  const int tg = t & 255;      // thread index within group
  char* const Ab = pool + 65536 + kh * 8192;
  char* const Bb = pool + kh * 32768;

  // A-load mapping: thread -> rows {ar, ar+32}, float4 column ac4 (coalesced 128B/8thr)
  const int ar = tg >> 3;            // 0..31
  const int ac4 = tg & 7;            // 0..7
  const float* xr0 = x + (size_t)(m0 + ar) * L_DIM + kh * 2048 + ac4 * 4;
  const float* xr1 = xr0 + (size_t)32 * L_DIM;
  // bf16 LDS A layout: [64 rows][4 slots of 16B], slot = (k16) ^ ((row>>1)&3)
  const int aswz = ((ac4 >> 1) ^ ((ar >> 1) & 3)) * 16 + (ac4 & 1) * 8;
  const int awoff0 = ar * 64 + aswz;          // ((ar+32)>>1)&3 == (ar>>1)&3
  const int awoff1 = (ar + 32) * 64 + aswz;

  // ---- prologue: A(0)->aP, B(0), A(1)->aQ, write A(0) ----
  float4 aP0 = *(const float4*)(xr0);
  float4 aP1 = *(const float4*)(xr1);
#pragma unroll
  for (int i = 0; i < 4; ++i) {
    const int j = wq * 4 + i;
    gload_lds16(fragB + ((size_t)(kh * 64) * 16 + j) * 512 + l * 8, Bb + j * 1024);
  }
  float4 aQ0 = *(const float4*)(xr0 + 32);
  float4 aQ1 = *(const float4*)(xr1 + 32);
  asm volatile("s_waitcnt vmcnt(0)" ::: "memory");
  store_bf4(Ab + awoff0, aP0);
  store_bf4(Ab + awoff1, aP1);
  asm volatile("s_waitcnt lgkmcnt(0)" ::: "memory");
  __builtin_amdgcn_s_barrier();

  f32x4 acc[2][8] = {};

  for (int s = 0; s < 64; ++s) {
    asm volatile("s_waitcnt vmcnt(0)" ::: "memory");   // B(s) in LDS; A(s+1) in regs
    __builtin_amdgcn_s_barrier();
    __builtin_amdgcn_sched_barrier(0);
    if (s < 63) {                                      // issue B(s+1)
      const int nb = (s + 1) & 1;
      const size_t fb = (size_t)(kh * 64 + s + 1) * 16;
#pragma unroll
      for (int i = 0; i < 4; ++i) {
        const int j = wq * 4 + i;
        gload_lds16(fragB + (fb + j) * 512 + l * 8, Bb + nb * 16384 + j * 1024);
      }
    }
    __builtin_amdgcn_sched_barrier(0);
    if (s < 63) {                                      // ds_write A(s+1) (held in regs)
      char* d = Ab + ((s + 1) & 1) * 4096;
      if (s & 1) { store_bf4(d + awoff0, aP0); store_bf4(d + awoff1, aP1); }
      else       { store_bf4(d + awoff0, aQ0); store_bf4(d + awoff1, aQ1); }
    }
    if (s < 62) {                                      // load A(s+2) into dead set
      const float4* p0 = (const float4*)(xr0 + (s + 2) * 32);
      const float4* p1 = (const float4*)(xr1 + (s + 2) * 32);
      if (s & 1) { aQ0 = *p0; aQ1 = *p1; } else { aP0 = *p0; aP1 = *p1; }
    }
    __builtin_amdgcn_sched_barrier(0);
    // compute stage s (one kstep of 32)
    const char* bA = Ab + (s & 1) * 4096;
    const char* bB = Bb + (s & 1) * 16384;
    short8 af[2];
#pragma unroll
    for (int mi = 0; mi < 2; ++mi) {
      const int row = wm * 32 + mi * 16 + (l & 15);
      af[mi] = *(const short8*)(bA + row * 64 + (((l >> 4) ^ ((row >> 1) & 3)) * 16));
    }
#pragma unroll
    for (int nt = 0; nt < 8; ++nt) {
      const short8 bf = *(const short8*)(bB + (wn * 8 + nt) * 1024 + l * 16);
#pragma unroll
      for (int mi = 0; mi < 2; ++mi)
        acc[mi][nt] = __builtin_amdgcn_mfma_f32_16x16x32_bf16(af[mi], bf, acc[mi][nt], 0, 0, 0);
    }
    asm volatile("s_waitcnt lgkmcnt(0)" ::: "memory");
    __builtin_amdgcn_s_barrier();
  }

  // ---- combine k-halves (B pool is free), write h_s bf16 pre-swizzled ----
  if (kh == 1) {
#pragma unroll
    for (int mi = 0; mi < 2; ++mi)
#pragma unroll
      for (int rr = 0; rr < 4; ++rr) {
        const int rl = wm * 32 + mi * 16 + (l >> 4) * 4 + rr;
#pragma unroll
        for (int nt = 0; nt < 8; ++nt) {
          const int col = wn * 128 + nt * 16 + (l & 15);
          *(float*)(pool + rl * 1024 + (col ^ ((rl & 3) << 2)) * 4) = acc[mi][nt][rr];
        }
      }
  }
  asm volatile("s_waitcnt lgkmcnt(0)" ::: "memory");
  __builtin_amdgcn_s_barrier();
  if (kh == 0) {
#pragma unroll
    for (int mi = 0; mi < 2; ++mi)
#pragma unroll
      for (int rr = 0; rr < 4; ++rr) {
        const int rl = wm * 32 + mi * 16 + (l >> 4) * 4 + rr;
        const int swz = (rl & 7) << 3;
        u16* hp = h_s + (size_t)(m0 + rl) * H_DIM;
#pragma unroll
        for (int nt = 0; nt < 8; ++nt) {
          const int col = wn * 128 + nt * 16 + (l & 15);
          const float sum = acc[mi][nt][rr] +
              *(const float*)(pool + rl * 1024 + (col ^ ((rl & 3) << 2)) * 4);
          hp[col ^ swz] = f2bf(sum);
        }
      }
  }
}

// out = LayerNorm(relu(h @ W1 + b1)) * gamma + beta   (verbatim from R3, proven)
__global__ __launch_bounds__(256, 1) void gemm2_ln(const u16* __restrict__ h_s,
                                                   const u16* __restrict__ w1T,
                                                   const float* __restrict__ b1,
                                                   const float* __restrict__ gmm,
                                                   const float* __restrict__ bta,
                                                   float* __restrict__ out) {
  __shared__ __align__(16) u16 As[64 * 64];
  __shared__ __align__(16) u16 Bs[256 * 64];
  __shared__ float red_s[4][64];
  __shared__ float red_q[4][64];
  __shared__ float mean_s[64];
  __shared__ float rstd_s[64];
  const int t = threadIdx.x;
  const int lane = t & 63;
  const int w = t >> 6;
  const int m0 = blockIdx.x * 64;
  const int bn = t >> 3;
  const int binner = (t & 7) * 8;

  f32x4 acc[4][4] = {};
  for (int kt = 0; kt < 4; ++kt) {
    __syncthreads();
#pragma unroll
    for (int r = 0; r < 2; ++r) {
      const u16* gp = h_s + (size_t)(m0 + r * 32 + bn) * H_DIM + kt * 64 + binner;
      gload_lds16(gp, &As[(r * 256 + w * 64) * 8]);
    }
#pragma unroll
    for (int r = 0; r < 8; ++r) {
      const u16* gp = w1T + (size_t)(r * 32 + bn) * H_DIM + kt * 64 + binner;
      gload_lds16(gp, &Bs[(r * 256 + w * 64) * 8]);
    }
    __syncthreads();
#pragma unroll
    for (int ks = 0; ks < 2; ++ks) {
      const int kb = ks * 64 + ((lane >> 4) * 16);
      short8 af[4], bf[4];
#pragma unroll
      for (int mi = 0; mi < 4; ++mi) {
        const int row = mi * 16 + (lane & 15);
        af[mi] = *reinterpret_cast<const short8*>(
            reinterpret_cast<const char*>(As) + row * 128 + (kb ^ ((row & 7) << 4)));
      }
#pragma unroll
      for (int ni = 0; ni < 4; ++ni) {
        const int n = w * 64 + ni * 16 + (lane & 15);
        bf[ni] = *reinterpret_cast<const short8*>(
            reinterpret_cast<const char*>(Bs) + n * 128 + (kb ^ ((n & 7) << 4)));
      }
#pragma unroll
      for (int mi = 0; mi < 4; ++mi)
#pragma unroll
        for (int ni = 0; ni < 4; ++ni)
          acc[mi][ni] = __builtin_amdgcn_mfma_f32_16x16x32_bf16(af[mi], bf[ni], acc[mi][ni], 0, 0, 0);
    }
  }
  const int cbase = w * 64 + (lane & 15);
  float cb[4];
#pragma unroll
  for (int ni = 0; ni < 4; ++ni) cb[ni] = b1[cbase + ni * 16];
#pragma unroll
  for (int mi = 0; mi < 4; ++mi)
#pragma unroll
    for (int ni = 0; ni < 4; ++ni)
#pragma unroll
      for (int r = 0; r < 4; ++r)
        acc[mi][ni][r] = fmaxf(acc[mi][ni][r] + cb[ni], 0.0f);
#pragma unroll
  for (int mi = 0; mi < 4; ++mi) {
#pragma unroll
    for (int r = 0; r < 4; ++r) {
      float s = 0.f, q = 0.f;
#pragma unroll
      for (int ni = 0; ni < 4; ++ni) { const float v = acc[mi][ni][r]; s += v; q += v * v; }
#pragma unroll
      for (int msk = 1; msk < 16; msk <<= 1) { s += __shfl_xor(s, msk); q += __shfl_xor(q, msk); }
      if ((lane & 15) == 0) {
        const int row = mi * 16 + (lane >> 4) * 4 + r;
        red_s[w][row] = s;
        red_q[w][row] = q;
      }
    }
  }
  __syncthreads();
  if (t < 64) {
    const float s = red_s[0][t] + red_s[1][t] + red_s[2][t] + red_s[3][t];
    const float q = red_q[0][t] + red_q[1][t] + red_q[2][t] + red_q[3][t];
    const float mu = s * (1.0f / 256.0f);
    const float var = q * (1.0f / 256.0f) - mu * mu;
    mean_s[t] = mu;
    rstd_s[t] = rsqrtf(var + LN_EPS);
  }
  __syncthreads();
  float cg[4], cbt[4];
#pragma unroll
  for (int ni = 0; ni < 4; ++ni) { cg[ni] = gmm[cbase + ni * 16]; cbt[ni] = bta[cbase + ni * 16]; }
#pragma unroll
  for (int mi = 0; mi < 4; ++mi) {
#pragma unroll
    for (int r = 0; r < 4; ++r) {
      const int row = mi * 16 + (lane >> 4) * 4 + r;
      const float mu = mean_s[row];
      const float rs = rstd_s[row];
      float* op = out + (size_t)(m0 + row) * H_DIM;
#pragma unroll
      for (int ni = 0; ni < 4; ++ni)
        op[cbase + ni * 16] = cg[ni] * (acc[mi][ni][r] - mu) * rs + cbt[ni];
    }
  }
}

extern "C" void kernel_launch(void* const* d_in, const int* in_sizes, int n_in,
                              void* d_out, int out_size, void* d_ws, size_t ws_size,
                              hipStream_t stream) {
  const float* x    = (const float*)d_in[0];
  const float* emb  = (const float*)d_in[1];
  const float* W1   = (const float*)d_in[2];
  const float* b1   = (const float*)d_in[3];
  const float* gmm  = (const float*)d_in[4];
  const float* bta  = (const float*)d_in[5];
  const int*   gidx = (const int*)d_in[6];
  float* out = (float*)d_out;

  char* ws = (char*)d_ws;
  u16* fragB = (u16*)ws;                                   // [128 ksteps][16 nt][64][8] = 2 MB
  u16* w1T   = (u16*)(ws + (size_t)H_DIM * L_DIM * 2);     // [256][256] bf16 = 128 KB
  u16* h_s   = (u16*)(ws + (size_t)H_DIM * L_DIM * 2
                          + (size_t)H_DIM * H_DIM * 2);    // [16384][256] bf16 = 8 MB

  prep_frag<<<512, 256, 0, stream>>>(emb, gidx, fragB);
  prep_tr<<<dim3(H_DIM / 64, H_DIM / 64), 256, 0, stream>>>(W1, nullptr, w1T, H_DIM, H_DIM);
  gemm1<<<256, 512, 0, stream>>>(x, fragB, h_s);
  gemm2_ln<<<256, 256, 0, stream>>>(h_s, w1T, b1, gmm, bta, out);
}

// Round 10
// 140.950 us; speedup vs baseline: 1.0352x; 1.0352x over previous
//
#include <hip/hip_runtime.h>
#include <stdint.h>

#define B_DIM 16384
#define L_DIM 4096
#define H_DIM 256
#define LN_EPS 1e-5f

typedef unsigned short u16;
typedef __attribute__((ext_vector_type(4))) float f32x4;
typedef __attribute__((ext_vector_type(8))) short short8;

__device__ __forceinline__ u16 f2bf(float f) {
  union { float f; uint32_t u; } v; v.f = f;
  uint32_t u = v.u;
  u += 0x7FFFu + ((u >> 16) & 1u);   // round-to-nearest-even
  return (u16)(u >> 16);
}

__device__ __forceinline__ void gload_lds16(const void* g, void* l) {
  __builtin_amdgcn_global_load_lds((const __attribute__((address_space(1))) void*)g,
                                   (__attribute__((address_space(3))) void*)l, 16, 0, 0);
}

// Fragment-major prep (gathered emb / plain W1):
// frag = kstep*16 + nt;  dst[frag][lane][j] = bf16(src[row][nt*16 + (lane&15)])
// row = idx ? idx[kstep*32 + (lane>>4)*8 + j] : (kstep*32 + (lane>>4)*8 + j)
__global__ __launch_bounds__(256) void prep_frag(const float* __restrict__ src,
                                                 const int* __restrict__ idx,
                                                 u16* __restrict__ dst) {
  const int t = threadIdx.x;
  const int l = t & 63;
  const int w = t >> 6;
  const int frag = blockIdx.x * 4 + w;
  const int kstep = frag >> 4;
  const int nt = frag & 15;
  const int n = nt * 16 + (l & 15);
  const int kbase = kstep * 32 + (l >> 4) * 8;
  short8 v;
#pragma unroll
  for (int j = 0; j < 8; ++j) {
    const int k = kbase + j;
    const int g = idx ? idx[k] : k;
    v[j] = (short)f2bf(src[(size_t)g * H_DIM + n]);
  }
  *reinterpret_cast<short8*>(dst + ((size_t)frag * 64 + l) * 8) = v;
}

// Fused: h = x @ feat (bf16 MFMA, K=4096), then out = LN(relu(h @ W1 + b1)).
// BM=32, 256 thr = 4 waves (wm x wn): wave owns 16 rows x 128 cols.
// Sync structure: EXACT R7 two-barrier stage (proven): top vmcnt(0)+barrier,
// issue next-stage loads, compute, lgkmcnt(0)+barrier. (R9's single-barrier
// failed: hipcc sinks register-only MFMAs + their lgkm waits past inline-asm
// barriers, leaving ds_reads pending when the buffer is overwritten.)
// CHANGE vs R7: A (x) is DIRECT global->reg, no LDS round-trip. Lane l reads
// row l&15, k=(l>>4)*8: the wave covers 16 rows x 128B fully (coalesced across
// the float4 pair). P/Q register sets alternate via 2x-unrolled loop (static
// indexing). Removes A ds_write/ds_read + 2 gloads from every stage.
// LDS 80KB: B dbuf 2x32KB @0, h-tile 16KB @65536 -> 2 blocks/CU at grid 512
// (cross-block overlap is the latency hider; 1-block/CU rounds R2/R6/R8 were
// all ~2x slower).
__global__ __launch_bounds__(256, 2) void fused(const float* __restrict__ x,
                                                const u16* __restrict__ fragB,
                                                const u16* __restrict__ fragW,
                                                const float* __restrict__ b1,
                                                const float* __restrict__ gmm,
                                                const float* __restrict__ bta,
                                                float* __restrict__ out) {
  __shared__ __align__(16) char pool[81920];   // B: 2x32KB @0; h-tile: 16KB @65536
  const int t = threadIdx.x;
  const int l = t & 63;
  const int w = t >> 6;       // 0..3
  const int wm = w >> 1;      // 0..1  m-slice (16 rows)
  const int wn = w & 1;       // 0..1  n-half (128 cols)
  const int m0 = blockIdx.x * 32;
  char* const htile = pool + 65536;

  // per-lane A source: row = wm*16 + (l&15), k base = (l>>4)*8
  const float* xrow = x + (size_t)(m0 + wm * 16 + (l & 15)) * L_DIM + ((l >> 4) * 8);

  f32x4 acc[8] = {};

  auto mk_af = [&](const float4& u, const float4& v) {
    short8 af;
    af[0] = (short)f2bf(u.x); af[1] = (short)f2bf(u.y);
    af[2] = (short)f2bf(u.z); af[3] = (short)f2bf(u.w);
    af[4] = (short)f2bf(v.x); af[5] = (short)f2bf(v.y);
    af[6] = (short)f2bf(v.z); af[7] = (short)f2bf(v.w);
    return af;
  };

  // ---- prologue: issue B(0) gloads; load A(0) into P regs ----
#pragma unroll
  for (int i = 0; i < 8; ++i) {
    const int j = w * 8 + i;                             // frag 0..31 of stage 0
    gload_lds16(fragB + (size_t)j * 512 + l * 8, pool + j * 1024);
  }
  float4 aP0 = *(const float4*)(xrow);
  float4 aP1 = *(const float4*)(xrow + 4);
  float4 aP2 = *(const float4*)(xrow + 32);
  float4 aP3 = *(const float4*)(xrow + 36);
  float4 aQ0 = {}, aQ1 = {}, aQ2 = {}, aQ3 = {};

  // two-barrier stage (R7-proven): compute from AC, prefetch s+1 into AN
  auto stage = [&](int S, const float4& AC0, const float4& AC1,
                   const float4& AC2, const float4& AC3,
                   float4& AN0, float4& AN1, float4& AN2, float4& AN3) {
    asm volatile("s_waitcnt vmcnt(0)" ::: "memory");     // stage-S B + A regs done
    __builtin_amdgcn_s_barrier();
    __builtin_amdgcn_sched_barrier(0);
    if (S < 63) {                                        // issue stage S+1
      const u16* srcB = fragB + (size_t)(S + 1) * 32 * 512;
      char* dstB = pool + ((S + 1) & 1) * 32768;
#pragma unroll
      for (int i = 0; i < 8; ++i) {
        const int j = w * 8 + i;
        gload_lds16(srcB + (size_t)j * 512 + l * 8, dstB + j * 1024);
      }
      const float* xn = xrow + (S + 1) * 64;
      AN0 = *(const float4*)(xn);
      AN1 = *(const float4*)(xn + 4);
      AN2 = *(const float4*)(xn + 32);
      AN3 = *(const float4*)(xn + 36);
    }
    __builtin_amdgcn_sched_barrier(0);                   // pin issues before compute
    const char* bB = pool + (S & 1) * 32768;
    {
      const short8 af = mk_af(AC0, AC1);                 // ks=0
#pragma unroll
      for (int nt = 0; nt < 8; ++nt) {
        const short8 bf = *(const short8*)(bB + (wn * 8 + nt) * 1024 + l * 16);
        acc[nt] = __builtin_amdgcn_mfma_f32_16x16x32_bf16(af, bf, acc[nt], 0, 0, 0);
      }
    }
    {
      const short8 af = mk_af(AC2, AC3);                 // ks=1
#pragma unroll
      for (int nt = 0; nt < 8; ++nt) {
        const short8 bf = *(const short8*)(bB + (16 + wn * 8 + nt) * 1024 + l * 16);
        acc[nt] = __builtin_amdgcn_mfma_f32_16x16x32_bf16(af, bf, acc[nt], 0, 0, 0);
      }
    }
    asm volatile("s_waitcnt lgkmcnt(0)" ::: "memory");   // reads done before overwrite
    __builtin_amdgcn_s_barrier();
  };

  for (int sp = 0; sp < 32; ++sp) {                      // 64 stages, P/Q static
    stage(sp * 2,     aP0, aP1, aP2, aP3, aQ0, aQ1, aQ2, aQ3);
    stage(sp * 2 + 1, aQ0, aQ1, aQ2, aQ3, aP0, aP1, aP2, aP3);
  }

  // ---- GEMM2 prologue: issue W(0) (L2-resident), write h tile to LDS ----
#pragma unroll
  for (int i = 0; i < 8; ++i) {
    const int j = w * 8 + i;
    gload_lds16(fragW + (size_t)j * 512 + l * 8, pool + j * 1024);
  }
  // h tile (bf16, XOR-swizzled 16B slots) @ htile (32 rows x 512B = 16KB)
  const int hrow_base = wm * 16 + ((l >> 4) << 2);
#pragma unroll
  for (int rr = 0; rr < 4; ++rr) {
    const int row = hrow_base + rr;
#pragma unroll
    for (int nt = 0; nt < 8; ++nt) {
      const int col = wn * 128 + nt * 16 + (l & 15);
      const int ls = (col >> 3) ^ (row & 15);
      *(u16*)(htile + row * 512 + ls * 16 + (col & 7) * 2) = f2bf(acc[nt][rr]);
    }
  }
  asm volatile("s_waitcnt lgkmcnt(0)" ::: "memory");     // h-tile writes done
  __builtin_amdgcn_s_barrier();

  const int arow = wm * 16 + (l & 15);
  f32x4 acc2[8] = {};
  for (int kt = 0; kt < 4; ++kt) {
    asm volatile("s_waitcnt vmcnt(0)" ::: "memory");     // W(kt) landed
    __builtin_amdgcn_s_barrier();
    __builtin_amdgcn_sched_barrier(0);
    if (kt < 3) {
      const u16* srcW = fragW + (size_t)(kt + 1) * 32 * 512;
#pragma unroll
      for (int i = 0; i < 8; ++i) {
        const int j = w * 8 + i;
        gload_lds16(srcW + (size_t)j * 512 + l * 8,
                    pool + ((kt + 1) & 1) * 32768 + j * 1024);
      }
    }
    __builtin_amdgcn_sched_barrier(0);
    const char* bW = pool + (kt & 1) * 32768;
#pragma unroll
    for (int ksi = 0; ksi < 2; ++ksi) {
      const int ks = kt * 2 + ksi;                       // 0..7
      const short8 af = *(const short8*)(
          htile + arow * 512 + (((ks * 4 + (l >> 4)) ^ (arow & 15)) * 16));
#pragma unroll
      for (int nt = 0; nt < 8; ++nt) {
        const short8 bf = *(const short8*)(bW + (ksi * 16 + wn * 8 + nt) * 1024 + l * 16);
        acc2[nt] = __builtin_amdgcn_mfma_f32_16x16x32_bf16(af, bf, acc2[nt], 0, 0, 0);
      }
    }
    asm volatile("s_waitcnt lgkmcnt(0)" ::: "memory");
    __builtin_amdgcn_s_barrier();
  }

  // ---- bias + relu + LN + store ----
  float bv[8];
#pragma unroll
  for (int nt = 0; nt < 8; ++nt) bv[nt] = b1[wn * 128 + nt * 16 + (l & 15)];
  float s4[4], q4[4];
#pragma unroll
  for (int rr = 0; rr < 4; ++rr) {
    float s = 0.f, q = 0.f;
#pragma unroll
    for (int nt = 0; nt < 8; ++nt) {
      const float v = fmaxf(acc2[nt][rr] + bv[nt], 0.f);
      acc2[nt][rr] = v; s += v; q += v * v;
    }
#pragma unroll
    for (int m = 1; m < 16; m <<= 1) { s += __shfl_xor(s, m); q += __shfl_xor(q, m); }
    s4[rr] = s; q4[rr] = q;
  }
  float* lnred = (float*)pool;                 // [2][32][2] f32 (B pool free now)
  if ((l & 15) == 0) {
#pragma unroll
    for (int rr = 0; rr < 4; ++rr) {
      const int row = hrow_base + rr;
      lnred[(wn * 32 + row) * 2 + 0] = s4[rr];
      lnred[(wn * 32 + row) * 2 + 1] = q4[rr];
    }
  }
  __syncthreads();
  float gg[8], bb[8];
#pragma unroll
  for (int nt = 0; nt < 8; ++nt) {
    const int col = wn * 128 + nt * 16 + (l & 15);
    gg[nt] = gmm[col]; bb[nt] = bta[col];
  }
#pragma unroll
  for (int rr = 0; rr < 4; ++rr) {
    const int row = hrow_base + rr;
    const float S = lnred[row * 2 + 0] + lnred[(32 + row) * 2 + 0];
    const float Q = lnred[row * 2 + 1] + lnred[(32 + row) * 2 + 1];
    const float mu = S * (1.0f / 256.0f);
    const float rstd = rsqrtf(Q * (1.0f / 256.0f) - mu * mu + LN_EPS);
    float* op = out + (size_t)(m0 + row) * H_DIM;
#pragma unroll
    for (int nt = 0; nt < 8; ++nt) {
      const int col = wn * 128 + nt * 16 + (l & 15);
      op[col] = gg[nt] * (acc2[nt][rr] - mu) * rstd + bb[nt];
    }
  }
}

extern "C" void kernel_launch(void* const* d_in, const int* in_sizes, int n_in,
                              void* d_out, int out_size, void* d_ws, size_t ws_size,
                              hipStream_t stream) {
  const float* x    = (const float*)d_in[0];
  const float* emb  = (const float*)d_in[1];
  const float* W1   = (const float*)d_in[2];
  const float* b1   = (const float*)d_in[3];
  const float* gmm  = (const float*)d_in[4];
  const float* bta  = (const float*)d_in[5];
  const int*   gidx = (const int*)d_in[6];
  float* out = (float*)d_out;

  char* ws = (char*)d_ws;
  u16* fragB = (u16*)ws;                                   // [128 ksteps][16 nt][64][8] = 2 MB
  u16* fragW = (u16*)(ws + (size_t)H_DIM * L_DIM * 2);     // [8 ksteps][16 nt][64][8] = 128 KB

  prep_frag<<<512, 256, 0, stream>>>(emb, gidx, fragB);    // 2048 frags
  prep_frag<<<32, 256, 0, stream>>>(W1, nullptr, fragW);   // 128 frags
  fused<<<512, 256, 0, stream>>>(x, fragB, fragW, b1, gmm, bta, out);
}

// Round 11
// 108.886 us; speedup vs baseline: 1.3401x; 1.2945x over previous
//
#include <hip/hip_runtime.h>
#include <stdint.h>

#define B_DIM 16384
#define L_DIM 4096
#define H_DIM 256
#define LN_EPS 1e-5f

typedef unsigned short u16;
typedef __attribute__((ext_vector_type(4))) float f32x4;
typedef __attribute__((ext_vector_type(8))) short short8;

__device__ __forceinline__ u16 f2bf(float f) {
  union { float f; uint32_t u; } v; v.f = f;
  uint32_t u = v.u;
  u += 0x7FFFu + ((u >> 16) & 1u);   // round-to-nearest-even
  return (u16)(u >> 16);
}

__device__ __forceinline__ short8 cvt8(const float4& u, const float4& v) {
  short8 o;
  o[0] = (short)f2bf(u.x); o[1] = (short)f2bf(u.y);
  o[2] = (short)f2bf(u.z); o[3] = (short)f2bf(u.w);
  o[4] = (short)f2bf(v.x); o[5] = (short)f2bf(v.y);
  o[6] = (short)f2bf(v.z); o[7] = (short)f2bf(v.w);
  return o;
}

__device__ __forceinline__ void gload_lds16(const void* g, void* l) {
  __builtin_amdgcn_global_load_lds((const __attribute__((address_space(1))) void*)g,
                                   (__attribute__((address_space(3))) void*)l, 16, 0, 0);
}

// Fragment-major prep (gathered emb / plain W1):
// frag = kstep*16 + nt;  dst[frag][lane][j] = bf16(src[row][nt*16 + (lane&15)])
// row = idx ? idx[kstep*32 + (lane>>4)*8 + j] : (kstep*32 + (lane>>4)*8 + j)
__global__ __launch_bounds__(256) void prep_frag(const float* __restrict__ src,
                                                 const int* __restrict__ idx,
                                                 u16* __restrict__ dst) {
  const int t = threadIdx.x;
  const int l = t & 63;
  const int w = t >> 6;
  const int frag = blockIdx.x * 4 + w;
  const int kstep = frag >> 4;
  const int nt = frag & 15;
  const int n = nt * 16 + (l & 15);
  const int kbase = kstep * 32 + (l >> 4) * 8;
  short8 v;
#pragma unroll
  for (int j = 0; j < 8; ++j) {
    const int k = kbase + j;
    const int g = idx ? idx[k] : k;
    v[j] = (short)f2bf(src[(size_t)g * H_DIM + n]);
  }
  *reinterpret_cast<short8*>(dst + ((size_t)frag * 64 + l) * 8) = v;
}

// Fused: h = x @ feat (bf16 MFMA, K=4096), then out = LN(relu(h @ W1 + b1)).
// BM=32, 256 thr = 4 waves; EACH wave owns all 32 rows x its 64 cols
// (acc[2][4]) -> every B fragment is LDS-read exactly ONCE per stage (R7 read
// them 2x), and A is staged bf16 (R8's reg-stage path) halving A read bytes:
// 84KB LDS port traffic/block-stage vs R7's 120KB. Schedule = R7/R8's proven
// two-barrier stage (R9's single-barrier is rejected: hipcc sinks MFMAs past
// inline-asm barriers). A global loads are wave-contiguous (R10 proved
// per-lane row-divergent VMEM is a 1.7x poison).
// LDS 72KB -> 2 blocks/CU at grid 512 (1-block/CU rounds R2/R6/R8 ~2x slower).
__global__ __launch_bounds__(256, 2) void fused(const float* __restrict__ x,
                                                const u16* __restrict__ fragB,
                                                const u16* __restrict__ fragW,
                                                const float* __restrict__ b1,
                                                const float* __restrict__ gmm,
                                                const float* __restrict__ bta,
                                                float* __restrict__ out) {
  __shared__ __align__(16) char pool[73728];  // B dbuf 2x32KB @0; A dbuf 2x4KB @65536
  const int t = threadIdx.x;
  const int l = t & 63;
  const int wv = t >> 6;                 // 0..3 : col group (64 cols)
  const int m0 = blockIdx.x * 32;
  char* const Ab = pool + 65536;

  // A staging map: thread t -> row sr=t>>3 (0..31), k-chunk sc=t&7 (8 floats).
  // 8 consecutive threads cover one row's 64 floats -> wave-contiguous.
  const int sr = t >> 3;
  const int sc = t & 7;
  const float* xsrc = x + (size_t)(m0 + sr) * L_DIM + sc * 8;
  // A LDS: [32 rows][8 slots x 16B], slot = sc ^ (row&7) (read uses same XOR;
  // rows r,r+8 share a slot -> 2-way bank alias = free).
  const int awoff = sr * 128 + ((sc ^ (sr & 7)) << 4);

  // ---- prologue: A(0)->P, issue B(0), A(1)->Q, write A(0), barrier ----
  float4 aP0 = *(const float4*)(xsrc);
  float4 aP1 = *(const float4*)(xsrc + 4);
#pragma unroll
  for (int i = 0; i < 8; ++i) {
    const int j = wv * 8 + i;            // j = ks*16+nt of stage 0
    gload_lds16(fragB + (size_t)((j >> 4) * 16 + (j & 15)) * 512 + l * 8,
                pool + j * 1024);
  }
  float4 aQ0 = *(const float4*)(xsrc + 64);
  float4 aQ1 = *(const float4*)(xsrc + 68);
  asm volatile("s_waitcnt vmcnt(0)" ::: "memory");
  *(short8*)(Ab + awoff) = cvt8(aP0, aP1);             // A(0) -> buf0
  asm volatile("s_waitcnt lgkmcnt(0)" ::: "memory");
  __builtin_amdgcn_s_barrier();

  f32x4 acc[2][4] = {};

  // two-barrier stage (R7/R8-proven). At stage S: LDS has A(S),B(S) in buf
  // (S&1); WR regs hold A(S+1) (ds_written now into buf (S+1)&1); LD regs are
  // dead (receive A(S+2) global loads).
  auto stage = [&](int S, const float4& WR0, const float4& WR1,
                   float4& LD0, float4& LD1) {
    asm volatile("s_waitcnt vmcnt(0)" ::: "memory");   // B(S) + A-globals landed
    __builtin_amdgcn_s_barrier();
    __builtin_amdgcn_sched_barrier(0);
    if (S < 63) {                                      // issue B(S+1)
      const u16* srcB = fragB + (size_t)(2 * (S + 1)) * 16 * 512;
      char* dstB = pool + ((S + 1) & 1) * 32768;
#pragma unroll
      for (int i = 0; i < 8; ++i) {
        const int j = wv * 8 + i;
        gload_lds16(srcB + (size_t)((j >> 4) * 16 + (j & 15)) * 512 + l * 8,
                    dstB + j * 1024);
      }
    }
    __builtin_amdgcn_sched_barrier(0);
    if (S < 63)                                        // ds_write A(S+1)
      *(short8*)(Ab + ((S + 1) & 1) * 4096 + awoff) = cvt8(WR0, WR1);
    if (S < 62) {                                      // load A(S+2) -> dead set
      const float* xn = xsrc + (S + 2) * 64;
      LD0 = *(const float4*)(xn);
      LD1 = *(const float4*)(xn + 4);
    }
    __builtin_amdgcn_sched_barrier(0);
    // compute stage S
    const char* bB = pool + (S & 1) * 32768;
    const char* bA = Ab + (S & 1) * 4096;
#pragma unroll
    for (int ks = 0; ks < 2; ++ks) {
      short8 af[2];
#pragma unroll
      for (int mi = 0; mi < 2; ++mi)
        af[mi] = *(const short8*)(bA + (mi * 16 + (l & 15)) * 128 +
                                  (((ks * 4 + (l >> 4)) ^ (l & 7)) << 4));
#pragma unroll
      for (int ntl = 0; ntl < 4; ++ntl) {
        const short8 bfv = *(const short8*)(bB + (ks * 16 + wv * 4 + ntl) * 1024 + l * 16);
#pragma unroll
        for (int mi = 0; mi < 2; ++mi)
          acc[mi][ntl] = __builtin_amdgcn_mfma_f32_16x16x32_bf16(af[mi], bfv, acc[mi][ntl], 0, 0, 0);
      }
    }
    asm volatile("s_waitcnt lgkmcnt(0)" ::: "memory");  // reads+A-write done
    __builtin_amdgcn_s_barrier();
  };

  for (int sp = 0; sp < 32; ++sp) {      // P/Q alternation, static indexing
    stage(sp * 2,     aQ0, aQ1, aP0, aP1);   // even S: write Q=A(S+1), load->P
    stage(sp * 2 + 1, aP0, aP1, aQ0, aQ1);   // odd  S: write P,        load->Q
  }

  // ---- GEMM2: 8 stages of BK=32. h-tile 16KB @pool[0]; W dbuf 2x16KB
  // @pool[16K..48K] (old B pool, dead after the final main-loop barrier). ----
#pragma unroll
  for (int i = 0; i < 4; ++i) {          // issue W(0): 16 frags
    const int j = wv * 4 + i;
    gload_lds16(fragW + (size_t)j * 512 + l * 8, pool + 16384 + j * 1024);
  }
  // write h tile (bf16, R7's slot-XOR layout): row*512 + ((col>>3)^(row&15))*16
#pragma unroll
  for (int mi = 0; mi < 2; ++mi)
#pragma unroll
    for (int rr = 0; rr < 4; ++rr) {
      const int row = mi * 16 + (l >> 4) * 4 + rr;
#pragma unroll
      for (int ntl = 0; ntl < 4; ++ntl) {
        const int col = wv * 64 + ntl * 16 + (l & 15);
        const int ls = (col >> 3) ^ (row & 15);
        *(u16*)(pool + row * 512 + ls * 16 + (col & 7) * 2) = f2bf(acc[mi][ntl][rr]);
      }
    }
  asm volatile("s_waitcnt lgkmcnt(0)" ::: "memory");
  __builtin_amdgcn_s_barrier();

  f32x4 acc2[2][4] = {};
  for (int kt = 0; kt < 8; ++kt) {
    asm volatile("s_waitcnt vmcnt(0)" ::: "memory");   // W(kt) landed
    __builtin_amdgcn_s_barrier();
    __builtin_amdgcn_sched_barrier(0);
    if (kt < 7) {
      const u16* srcW = fragW + (size_t)(kt + 1) * 16 * 512;
      char* dstW = pool + 16384 + ((kt + 1) & 1) * 16384;
#pragma unroll
      for (int i = 0; i < 4; ++i) {
        const int j = wv * 4 + i;
        gload_lds16(srcW + (size_t)j * 512 + l * 8, dstW + j * 1024);
      }
    }
    __builtin_amdgcn_sched_barrier(0);
    const char* bW = pool + 16384 + (kt & 1) * 16384;
    short8 af[2];
#pragma unroll
    for (int mi = 0; mi < 2; ++mi) {
      const int row = mi * 16 + (l & 15);
      af[mi] = *(const short8*)(pool + row * 512 +
                                (((kt * 4 + (l >> 4)) ^ (row & 15)) << 4));
    }
#pragma unroll
    for (int ntl = 0; ntl < 4; ++ntl) {
      const short8 bfv = *(const short8*)(bW + (wv * 4 + ntl) * 1024 + l * 16);
#pragma unroll
      for (int mi = 0; mi < 2; ++mi)
        acc2[mi][ntl] = __builtin_amdgcn_mfma_f32_16x16x32_bf16(af[mi], bfv, acc2[mi][ntl], 0, 0, 0);
    }
    asm volatile("s_waitcnt lgkmcnt(0)" ::: "memory");
    __builtin_amdgcn_s_barrier();
  }

  // ---- bias + relu + LN + store ----
  float bv[4], gg[4], bb[4];
#pragma unroll
  for (int ntl = 0; ntl < 4; ++ntl) {
    const int col = wv * 64 + ntl * 16 + (l & 15);
    bv[ntl] = b1[col]; gg[ntl] = gmm[col]; bb[ntl] = bta[col];
  }
  float* lnred = (float*)(pool + 49152);   // [4 wv][32 rows][2], region idle
#pragma unroll
  for (int mi = 0; mi < 2; ++mi)
#pragma unroll
    for (int rr = 0; rr < 4; ++rr) {
      float s = 0.f, q = 0.f;
#pragma unroll
      for (int ntl = 0; ntl < 4; ++ntl) {
        const float v = fmaxf(acc2[mi][ntl][rr] + bv[ntl], 0.f);
        acc2[mi][ntl][rr] = v; s += v; q += v * v;
      }
#pragma unroll
      for (int m = 1; m < 16; m <<= 1) { s += __shfl_xor(s, m); q += __shfl_xor(q, m); }
      if ((l & 15) == 0) {
        const int row = mi * 16 + (l >> 4) * 4 + rr;
        lnred[(wv * 32 + row) * 2 + 0] = s;
        lnred[(wv * 32 + row) * 2 + 1] = q;
      }
    }
  __syncthreads();
#pragma unroll
  for (int mi = 0; mi < 2; ++mi)
#pragma unroll
    for (int rr = 0; rr < 4; ++rr) {
      const int row = mi * 16 + (l >> 4) * 4 + rr;
      float S = 0.f, Q = 0.f;
#pragma unroll
      for (int w2 = 0; w2 < 4; ++w2) {
        S += lnred[(w2 * 32 + row) * 2 + 0];
        Q += lnred[(w2 * 32 + row) * 2 + 1];
      }
      const float mu = S * (1.0f / 256.0f);
      const float rstd = rsqrtf(Q * (1.0f / 256.0f) - mu * mu + LN_EPS);
      float* op = out + (size_t)(m0 + row) * H_DIM;
#pragma unroll
      for (int ntl = 0; ntl < 4; ++ntl) {
        const int col = wv * 64 + ntl * 16 + (l & 15);
        op[col] = gg[ntl] * (acc2[mi][ntl][rr] - mu) * rstd + bb[ntl];
      }
    }
}

extern "C" void kernel_launch(void* const* d_in, const int* in_sizes, int n_in,
                              void* d_out, int out_size, void* d_ws, size_t ws_size,
                              hipStream_t stream) {
  const float* x    = (const float*)d_in[0];
  const float* emb  = (const float*)d_in[1];
  const float* W1   = (const float*)d_in[2];
  const float* b1   = (const float*)d_in[3];
  const float* gmm  = (const float*)d_in[4];
  const float* bta  = (const float*)d_in[5];
  const int*   gidx = (const int*)d_in[6];
  float* out = (float*)d_out;

  char* ws = (char*)d_ws;
  u16* fragB = (u16*)ws;                                   // [128 ksteps][16 nt][64][8] = 2 MB
  u16* fragW = (u16*)(ws + (size_t)H_DIM * L_DIM * 2);     // [8 ksteps][16 nt][64][8] = 128 KB

  prep_frag<<<512, 256, 0, stream>>>(emb, gidx, fragB);    // 2048 frags
  prep_frag<<<32, 256, 0, stream>>>(W1, nullptr, fragW);   // 128 frags
  fused<<<512, 256, 0, stream>>>(x, fragB, fragW, b1, gmm, bta, out);
}

// Round 12
// 106.116 us; speedup vs baseline: 1.3750x; 1.0261x over previous
//
#include <hip/hip_runtime.h>
#include <stdint.h>

#define B_DIM 16384
#define L_DIM 4096
#define H_DIM 256
#define LN_EPS 1e-5f
// bijective 4-bit slot permutation from the low 4 row bits
#define PERM4(r) ((((r) & 7) << 1) | (((r) >> 3) & 1))

typedef unsigned short u16;
typedef __attribute__((ext_vector_type(4))) float f32x4;
typedef __attribute__((ext_vector_type(8))) short short8;

__device__ __forceinline__ u16 f2bf(float f) {
  union { float f; uint32_t u; } v; v.f = f;
  uint32_t u = v.u;
  u += 0x7FFFu + ((u >> 16) & 1u);   // round-to-nearest-even
  return (u16)(u >> 16);
}

__device__ __forceinline__ short8 cvt8(const float4& u, const float4& v) {
  short8 o;
  o[0] = (short)f2bf(u.x); o[1] = (short)f2bf(u.y);
  o[2] = (short)f2bf(u.z); o[3] = (short)f2bf(u.w);
  o[4] = (short)f2bf(v.x); o[5] = (short)f2bf(v.y);
  o[6] = (short)f2bf(v.z); o[7] = (short)f2bf(v.w);
  return o;
}

__device__ __forceinline__ void gload_lds16(const void* g, void* l) {
  __builtin_amdgcn_global_load_lds((const __attribute__((address_space(1))) void*)g,
                                   (__attribute__((address_space(3))) void*)l, 16, 0, 0);
}

// Fragment-major prep (gathered emb / plain W1):
// frag = kstep*16 + nt;  dst[frag][lane][j] = bf16(src[row][nt*16 + (lane&15)])
// row = idx ? idx[kstep*32 + (lane>>4)*8 + j] : (kstep*32 + (lane>>4)*8 + j)
__global__ __launch_bounds__(256) void prep_frag(const float* __restrict__ src,
                                                 const int* __restrict__ idx,
                                                 u16* __restrict__ dst) {
  const int t = threadIdx.x;
  const int l = t & 63;
  const int w = t >> 6;
  const int frag = blockIdx.x * 4 + w;
  const int kstep = frag >> 4;
  const int nt = frag & 15;
  const int n = nt * 16 + (l & 15);
  const int kbase = kstep * 32 + (l >> 4) * 8;
  short8 v;
#pragma unroll
  for (int j = 0; j < 8; ++j) {
    const int k = kbase + j;
    const int g = idx ? idx[k] : k;
    v[j] = (short)f2bf(src[(size_t)g * H_DIM + n]);
  }
  *reinterpret_cast<short8*>(dst + ((size_t)frag * 64 + l) * 8) = v;
}

// Fused: h = x @ feat (bf16 MFMA, K=4096), then out = LN(relu(h @ W1 + b1)).
// BM=32, 256 thr = 4 waves; wave owns all 32 rows x its 64 cols (acc[2][4]).
// KEY CHANGE vs R11: B comes from fragment-major fragB via per-wave COALESCED
// register loads (fragB + frag*1024 + lane*16 is contiguous 1KB/instr) into a
// P/Q register dbuf -- self-timed by compiler data-dep waits, no barriers.
// Only A (8KB f32/stage, R7's proven gload_lds + PERM4 swizzle) remains
// barrier-coupled: the per-stage drained set shrinks 40KB/10ops -> 8KB/2ops.
// Schedule: R7/R11's proven two-barrier stage, vmcnt(0) only (order-indep).
// LDS 80KB -> 2 blocks/CU at grid 512 (1-block/CU proven ~2x slower R6/R8).
__global__ __launch_bounds__(256, 2) void fused(const float* __restrict__ x,
                                                const u16* __restrict__ fragB,
                                                const u16* __restrict__ fragW,
                                                const float* __restrict__ b1,
                                                const float* __restrict__ gmm,
                                                const float* __restrict__ bta,
                                                float* __restrict__ out) {
  // GEMM2: h-tile 16K @0, W dbuf 32K @16K, lnred @49152. A dbuf 2x8K @65536.
  __shared__ __align__(16) char pool[81920];
  const int t = threadIdx.x;
  const int l = t & 63;
  const int wv = t >> 6;                 // 0..3 : col group (64 cols)
  const int m0 = blockIdx.x * 32;
  const float* xbase = x + (size_t)m0 * L_DIM;
  char* const Ab = pool + 65536;

  f32x4 acc[2][4] = {};
  short8 bP[8], bQ[8];

  // ---- prologue: issue A(0) gload_lds; load B(0) -> bP ----
#pragma unroll
  for (int i = 0; i < 2; ++i) {
    const int R = (wv * 2 + i) * 4 + (l >> 4);           // rows 8wv..8wv+7
    const int c16 = (l & 15) ^ PERM4(R);
    gload_lds16(xbase + (size_t)R * L_DIM + c16 * 4, Ab + (wv * 2 + i) * 1024);
  }
#pragma unroll
  for (int f = 0; f < 8; ++f) {                          // ks = f>>2, ntl = f&3
    const int frag = (f >> 2) * 16 + wv * 4 + (f & 3);
    bP[f] = *(const short8*)(fragB + (size_t)frag * 512 + l * 8);
  }

  // two-barrier stage (R7/R11-proven sync structure, unchanged)
  auto stage = [&](int S, short8 (&cur)[8], short8 (&nxt)[8]) {
    asm volatile("s_waitcnt vmcnt(0)" ::: "memory");     // A(S) in LDS, B(S) in regs
    __builtin_amdgcn_s_barrier();
    __builtin_amdgcn_sched_barrier(0);
    if (S < 63) {
#pragma unroll
      for (int i = 0; i < 2; ++i) {                      // issue A(S+1) -> LDS
        const int R = (wv * 2 + i) * 4 + (l >> 4);
        const int c16 = (l & 15) ^ PERM4(R);
        gload_lds16(xbase + (size_t)R * L_DIM + (S + 1) * 64 + c16 * 4,
                    Ab + ((S + 1) & 1) * 8192 + (wv * 2 + i) * 1024);
      }
#pragma unroll
      for (int f = 0; f < 8; ++f) {                      // B(S+1) -> nxt regs
        const int frag = (2 * (S + 1) + (f >> 2)) * 16 + wv * 4 + (f & 3);
        nxt[f] = *(const short8*)(fragB + (size_t)frag * 512 + l * 8);
      }
    }
    __builtin_amdgcn_sched_barrier(0);                   // pin issues before compute
    const char* bA = Ab + (S & 1) * 8192;
#pragma unroll
    for (int ks = 0; ks < 2; ++ks) {
      short8 af[2];
#pragma unroll
      for (int mi = 0; mi < 2; ++mi) {
        const int row = mi * 16 + (l & 15);
        const int p4 = PERM4(row);
        const int gs = ks * 8 + (l >> 4) * 2;
        const float4 a0 = *(const float4*)(bA + row * 256 + ((gs ^ p4) * 16));
        const float4 a1 = *(const float4*)(bA + row * 256 + (((gs + 1) ^ p4) * 16));
        af[mi] = cvt8(a0, a1);
      }
#pragma unroll
      for (int ntl = 0; ntl < 4; ++ntl)
#pragma unroll
        for (int mi = 0; mi < 2; ++mi)
          acc[mi][ntl] = __builtin_amdgcn_mfma_f32_16x16x32_bf16(
              af[mi], cur[ks * 4 + ntl], acc[mi][ntl], 0, 0, 0);
    }
    asm volatile("s_waitcnt lgkmcnt(0)" ::: "memory");   // A reads done pre-overwrite
    __builtin_amdgcn_s_barrier();
  };

  for (int sp = 0; sp < 32; ++sp) {                      // P/Q static alternation
    stage(sp * 2,     bP, bQ);
    stage(sp * 2 + 1, bQ, bP);
  }

  // ---- GEMM2 (R11-proven): h-tile @pool[0..16K], W dbuf @pool[16K..48K] ----
#pragma unroll
  for (int i = 0; i < 4; ++i) {          // issue W(0): 16 frags
    const int j = wv * 4 + i;
    gload_lds16(fragW + (size_t)j * 512 + l * 8, pool + 16384 + j * 1024);
  }
  // write h tile (bf16, slot-XOR layout): row*512 + ((col>>3)^(row&15))*16
#pragma unroll
  for (int mi = 0; mi < 2; ++mi)
#pragma unroll
    for (int rr = 0; rr < 4; ++rr) {
      const int row = mi * 16 + (l >> 4) * 4 + rr;
#pragma unroll
      for (int ntl = 0; ntl < 4; ++ntl) {
        const int col = wv * 64 + ntl * 16 + (l & 15);
        const int ls = (col >> 3) ^ (row & 15);
        *(u16*)(pool + row * 512 + ls * 16 + (col & 7) * 2) = f2bf(acc[mi][ntl][rr]);
      }
    }
  asm volatile("s_waitcnt lgkmcnt(0)" ::: "memory");
  __builtin_amdgcn_s_barrier();

  f32x4 acc2[2][4] = {};
  for (int kt = 0; kt < 8; ++kt) {
    asm volatile("s_waitcnt vmcnt(0)" ::: "memory");     // W(kt) landed
    __builtin_amdgcn_s_barrier();
    __builtin_amdgcn_sched_barrier(0);
    if (kt < 7) {
      const u16* srcW = fragW + (size_t)(kt + 1) * 16 * 512;
      char* dstW = pool + 16384 + ((kt + 1) & 1) * 16384;
#pragma unroll
      for (int i = 0; i < 4; ++i) {
        const int j = wv * 4 + i;
        gload_lds16(srcW + (size_t)j * 512 + l * 8, dstW + j * 1024);
      }
    }
    __builtin_amdgcn_sched_barrier(0);
    const char* bW = pool + 16384 + (kt & 1) * 16384;
    short8 af[2];
#pragma unroll
    for (int mi = 0; mi < 2; ++mi) {
      const int row = mi * 16 + (l & 15);
      af[mi] = *(const short8*)(pool + row * 512 +
                                (((kt * 4 + (l >> 4)) ^ (row & 15)) << 4));
    }
#pragma unroll
    for (int ntl = 0; ntl < 4; ++ntl) {
      const short8 bfv = *(const short8*)(bW + (wv * 4 + ntl) * 1024 + l * 16);
#pragma unroll
      for (int mi = 0; mi < 2; ++mi)
        acc2[mi][ntl] = __builtin_amdgcn_mfma_f32_16x16x32_bf16(af[mi], bfv, acc2[mi][ntl], 0, 0, 0);
    }
    asm volatile("s_waitcnt lgkmcnt(0)" ::: "memory");
    __builtin_amdgcn_s_barrier();
  }

  // ---- bias + relu + LN + store (R11-proven) ----
  float bv[4], gg[4], bb[4];
#pragma unroll
  for (int ntl = 0; ntl < 4; ++ntl) {
    const int col = wv * 64 + ntl * 16 + (l & 15);
    bv[ntl] = b1[col]; gg[ntl] = gmm[col]; bb[ntl] = bta[col];
  }
  float* lnred = (float*)(pool + 49152);   // [4 wv][32 rows][2]
#pragma unroll
  for (int mi = 0; mi < 2; ++mi)
#pragma unroll
    for (int rr = 0; rr < 4; ++rr) {
      float s = 0.f, q = 0.f;
#pragma unroll
      for (int ntl = 0; ntl < 4; ++ntl) {
        const float v = fmaxf(acc2[mi][ntl][rr] + bv[ntl], 0.f);
        acc2[mi][ntl][rr] = v; s += v; q += v * v;
      }
#pragma unroll
      for (int m = 1; m < 16; m <<= 1) { s += __shfl_xor(s, m); q += __shfl_xor(q, m); }
      if ((l & 15) == 0) {
        const int row = mi * 16 + (l >> 4) * 4 + rr;
        lnred[(wv * 32 + row) * 2 + 0] = s;
        lnred[(wv * 32 + row) * 2 + 1] = q;
      }
    }
  __syncthreads();
#pragma unroll
  for (int mi = 0; mi < 2; ++mi)
#pragma unroll
    for (int rr = 0; rr < 4; ++rr) {
      const int row = mi * 16 + (l >> 4) * 4 + rr;
      float S = 0.f, Q = 0.f;
#pragma unroll
      for (int w2 = 0; w2 < 4; ++w2) {
        S += lnred[(w2 * 32 + row) * 2 + 0];
        Q += lnred[(w2 * 32 + row) * 2 + 1];
      }
      const float mu = S * (1.0f / 256.0f);
      const float rstd = rsqrtf(Q * (1.0f / 256.0f) - mu * mu + LN_EPS);
      float* op = out + (size_t)(m0 + row) * H_DIM;
#pragma unroll
      for (int ntl = 0; ntl < 4; ++ntl) {
        const int col = wv * 64 + ntl * 16 + (l & 15);
        op[col] = gg[ntl] * (acc2[mi][ntl][rr] - mu) * rstd + bb[ntl];
      }
    }
}

extern "C" void kernel_launch(void* const* d_in, const int* in_sizes, int n_in,
                              void* d_out, int out_size, void* d_ws, size_t ws_size,
                              hipStream_t stream) {
  const float* x    = (const float*)d_in[0];
  const float* emb  = (const float*)d_in[1];
  const float* W1   = (const float*)d_in[2];
  const float* b1   = (const float*)d_in[3];
  const float* gmm  = (const float*)d_in[4];
  const float* bta  = (const float*)d_in[5];
  const int*   gidx = (const int*)d_in[6];
  float* out = (float*)d_out;

  char* ws = (char*)d_ws;
  u16* fragB = (u16*)ws;                                   // [128 ksteps][16 nt][64][8] = 2 MB
  u16* fragW = (u16*)(ws + (size_t)H_DIM * L_DIM * 2);     // [8 ksteps][16 nt][64][8] = 128 KB

  prep_frag<<<512, 256, 0, stream>>>(emb, gidx, fragB);    // 2048 frags
  prep_frag<<<32, 256, 0, stream>>>(W1, nullptr, fragW);   // 128 frags
  fused<<<512, 256, 0, stream>>>(x, fragB, fragW, b1, gmm, bta, out);
}